// Round 3
// baseline (42651.535 us; speedup 1.0000x reference)
//
#include <hip/hip_runtime.h>
#include <hip/hip_fp16.h>

// Neural ODE (Dopri5, 64 steps), D=2048, H=8192.
// Round 3: single persistent kernel, 256 blocks x 1024 threads (1 block/CU).
// fp16 weights live in REGISTERS (64 VGPR/thread) for the whole integration;
// per-stage traffic is only the y/h vector broadcasts. Custom grid barrier
// (per-block flag, agent-scope atomics). Tableau state (y, k0..k4) in wave-0
// lane registers; 6 stages fully unrolled (static ks indexing).

constexpr int D = 2048;
constexpr int H = 8192;
constexpr int NSTEPS = 64;
constexpr int NBLK = 256;
constexpr int NTHR = 1024;

__device__ __forceinline__ float waveReduce64(float v) {
    #pragma unroll
    for (int off = 32; off; off >>= 1) v += __shfl_down(v, off, 64);
    return v;
}

__device__ __forceinline__ void gridBarrier(int* flags, int g, int bid, int tid) {
    __syncthreads();  // all waves done (drains vmcnt -> stores in flight retire)
    if (tid == 0)
        __hip_atomic_store(flags + bid * 16, g, __ATOMIC_RELEASE, __HIP_MEMORY_SCOPE_AGENT);
    if (tid < 64) {   // wave 0 polls all 256 flags (4 per lane)
        int spin = 0;
        for (;;) {
            bool ok = true;
            #pragma unroll
            for (int j = 0; j < 4; ++j) {
                int v = __hip_atomic_load(flags + (tid * 4 + j) * 16,
                                          __ATOMIC_ACQUIRE, __HIP_MEMORY_SCOPE_AGENT);
                ok &= (v >= g);   // poison 0xAAAAAAAA is negative -> keeps spinning
            }
            if (__all(ok)) break;
            if (++spin > (1 << 20)) break;  // fail loud (validation) over hang
            __builtin_amdgcn_s_sleep(1);
        }
    }
    __syncthreads();
    __builtin_amdgcn_fence(__ATOMIC_ACQUIRE, "agent");
}

__global__ __launch_bounds__(NTHR, 4) void k_ode(
    const float* __restrict__ x,  const float* __restrict__ W1,
    const float* __restrict__ wt, const float* __restrict__ b1,
    const float* __restrict__ W2, const float* __restrict__ b2,
    float* __restrict__ out, float* __restrict__ yi_g,
    float* __restrict__ h_g, int* __restrict__ flags)
{
    __shared__ float ylds[D];    //  8 KB
    __shared__ float hlds[H];    // 32 KB
    __shared__ float part[16];

    const int tid  = threadIdx.x;
    const int bid  = blockIdx.x;
    const int wave = tid >> 6;
    const int lane = tid & 63;

    // ---- one-time: weights -> registers (fp16, adjacent-pair packing) ----
    // mv1: wave owns rows r0, r0+1 of W1; lane owns col pairs (j*128+2l, +1)
    const int r0 = bid * 32 + wave * 2;
    __half2 w1f0[16], w1f1[16];
    {
        const float2* s0 = (const float2*)(W1 + (size_t)r0 * D);
        const float2* s1 = (const float2*)(W1 + (size_t)(r0 + 1) * D);
        #pragma unroll
        for (int j = 0; j < 16; ++j) {
            float2 a = s0[j * 64 + lane];           // coalesced 512B/wave
            float2 b = s1[j * 64 + lane];
            w1f0[j] = __floats2half2_rn(a.x, a.y);
            w1f1[j] = __floats2half2_rn(b.x, b.y);
        }
    }
    // mv2: wave pair (2j,2j+1) owns W2 row bid*8+j; lane owns pairs
    // (j*256 + half*128 + 2l, +1)
    const int row2 = bid * 8 + (wave >> 1);
    const int half = wave & 1;
    __half2 w2f[32];
    {
        const float2* s = (const float2*)(W2 + (size_t)row2 * H);
        #pragma unroll
        for (int j = 0; j < 32; ++j) {
            float2 a = s[j * 128 + half * 64 + lane];
            w2f[j] = __floats2half2_rn(a.x, a.y);
        }
    }
    const float wt0 = wt[r0], wt1 = wt[r0 + 1];
    const float b10 = b1[r0], b11 = b1[r0 + 1];

    // wave-0 lanes 0..7 hold the block's 8 state rows entirely in registers
    const int myrow = bid * 8 + lane;
    float yreg = 0.f, b2r = 0.f;
    if (wave == 0 && lane < 8) { yreg = x[myrow]; b2r = b2[myrow]; }
    float k0 = 0, k1 = 0, k2 = 0, k3 = 0, k4 = 0;

    constexpr float dt = 1.0f / 64.0f;
    int g = 1;

    #pragma unroll 1
    for (int step = 0; step < NSTEPS; ++step) {
        const float t = step * dt;
        #pragma unroll
        for (int st = 0; st < 6; ++st) {
            constexpr float Cc[6] = {0.f, 0.2f, 0.3f, 0.8f, 8.f/9.f, 1.f};
            const float s = 1.0f - (t + Cc[st] * dt);

            // ---- stage y (2048 f32) into LDS ----
            if (st == 0 && step == 0) {
                ((float2*)ylds)[tid] = ((const float2*)x)[tid];
            } else {
                ylds[tid] = __hip_atomic_load(yi_g + tid, __ATOMIC_RELAXED,
                                              __HIP_MEMORY_SCOPE_AGENT);
                ylds[tid + 1024] = __hip_atomic_load(yi_g + tid + 1024,
                                              __ATOMIC_RELAXED, __HIP_MEMORY_SCOPE_AGENT);
            }
            __syncthreads();

            // ---- mv1: two W1 rows per wave, fully in-wave dot ----
            float a0 = 0.f, a1 = 0.f;
            #pragma unroll
            for (int j = 0; j < 16; ++j) {
                float2 yv = ((const float2*)ylds)[j * 64 + lane];
                float2 f0 = __half22float2(w1f0[j]);
                float2 f1 = __half22float2(w1f1[j]);
                a0 = fmaf(f0.x, yv.x, fmaf(f0.y, yv.y, a0));
                a1 = fmaf(f1.x, yv.x, fmaf(f1.y, yv.y, a1));
            }
            a0 = waveReduce64(a0);
            a1 = waveReduce64(a1);
            if (lane == 0) {
                float h0 = tanhf(fmaf(s, wt0, a0 + b10));
                float h1 = tanhf(fmaf(s, wt1, a1 + b11));
                __hip_atomic_store(h_g + r0, h0, __ATOMIC_RELAXED, __HIP_MEMORY_SCOPE_AGENT);
                __hip_atomic_store(h_g + r0 + 1, h1, __ATOMIC_RELAXED, __HIP_MEMORY_SCOPE_AGENT);
            }
            gridBarrier(flags, g++, bid, tid);

            // ---- stage h (8192 f32) into LDS ----
            #pragma unroll
            for (int i = 0; i < 8; ++i)
                hlds[tid + i * 1024] = __hip_atomic_load(h_g + tid + i * 1024,
                                              __ATOMIC_RELAXED, __HIP_MEMORY_SCOPE_AGENT);
            __syncthreads();

            // ---- mv2: half a W2 row per wave ----
            float acc = 0.f;
            #pragma unroll
            for (int j = 0; j < 32; ++j) {
                float2 hv = ((const float2*)hlds)[j * 128 + half * 64 + lane];
                float2 f = __half22float2(w2f[j]);
                acc = fmaf(f.x, hv.x, fmaf(f.y, hv.y, acc));
            }
            acc = waveReduce64(acc);
            if (lane == 0) part[wave] = acc;
            __syncthreads();

            // ---- tableau epilogue: wave 0, lanes 0..7 (all state in regs) ----
            if (wave == 0 && lane < 8) {
                const float k = -(part[lane * 2] + part[lane * 2 + 1] + b2r);
                float yo;
                if (st == 0) { k0 = k;
                    yo = fmaf(dt * 0.2f, k0, yreg); }
                else if (st == 1) { k1 = k;
                    yo = yreg + dt * (3.f/40.f*k0 + 9.f/40.f*k1); }
                else if (st == 2) { k2 = k;
                    yo = yreg + dt * (44.f/45.f*k0 - 56.f/15.f*k1 + 32.f/9.f*k2); }
                else if (st == 3) { k3 = k;
                    yo = yreg + dt * (19372.f/6561.f*k0 - 25360.f/2187.f*k1
                                    + 64448.f/6561.f*k2 - 212.f/729.f*k3); }
                else if (st == 4) { k4 = k;
                    yo = yreg + dt * (9017.f/3168.f*k0 - 355.f/33.f*k1
                                    + 46732.f/5247.f*k2 + 49.f/176.f*k3
                                    - 5103.f/18656.f*k4); }
                else {
                    yreg = yreg + dt * (35.f/384.f*k0 + 500.f/1113.f*k2
                                      + 125.f/192.f*k3 - 2187.f/6784.f*k4
                                      + 11.f/84.f*k);
                    yo = yreg;
                    if (step == NSTEPS - 1) out[myrow] = yreg;
                }
                __hip_atomic_store(yi_g + myrow, yo, __ATOMIC_RELAXED,
                                   __HIP_MEMORY_SCOPE_AGENT);
            }
            gridBarrier(flags, g++, bid, tid);
        }
    }
}

extern "C" void kernel_launch(void* const* d_in, const int* in_sizes, int n_in,
                              void* d_out, int out_size, void* d_ws, size_t ws_size,
                              hipStream_t stream) {
    const float* x  = (const float*)d_in[0];
    const float* W1 = (const float*)d_in[1];
    const float* wt = (const float*)d_in[2];
    const float* b1 = (const float*)d_in[3];
    const float* W2 = (const float*)d_in[4];
    const float* b2 = (const float*)d_in[5];
    float* out = (float*)d_out;

    float* ws   = (float*)d_ws;
    float* yi_g = ws;            // [D]
    float* h_g  = ws + D;        // [H]
    int*   flags = (int*)(ws + D + H);  // 256 * 16 ints (64B spacing)

    hipLaunchKernelGGL(k_ode, dim3(NBLK), dim3(NTHR), 0, stream,
                       x, W1, wt, b1, W2, b2, out, yi_g, h_g, flags);
}

// Round 7
// 9503.399 us; speedup vs baseline: 4.4880x; 4.4880x over previous
//
#include <hip/hip_runtime.h>
#include <hip/hip_fp16.h>

// Neural ODE (Dopri5, 64 steps), D=2048, H=8192.
// Round 4 design (fourth submit; three GPU-acquisition timeouts, never ran):
// persistent kernel, 256 blocks x 512 threads (1 block/CU, 2 waves/SIMD
// -> 256-VGPR budget). fp16 weights in REGISTERS (128 VGPR/thread, no spill).
// Fence-FREE grid barrier: relaxed agent atomics only + vmcnt(0) drain
// (round 3's acquire fences emitted buffer_inv -> L2 invalidated every poll
// iteration -> 42 ms; this removes all cache-invalidating ops).

constexpr int D = 2048;
constexpr int H = 8192;
constexpr int NSTEPS = 64;
constexpr int NBLK = 256;
constexpr int NTHR = 512;

__device__ __forceinline__ float waveReduce64(float v) {
    #pragma unroll
    for (int off = 32; off; off >>= 1) v += __shfl_down(v, off, 64);
    return v;
}

__device__ __forceinline__ void drainVM() {
    asm volatile("s_waitcnt vmcnt(0)" ::: "memory");
}

// Flat grid barrier, relaxed atomics only.
//  - data stores (relaxed, agent) are drained to the coherence point by each
//    wave's vmcnt(0) BEFORE it arrives at __syncthreads, so the flag store
//    (tid 0, after syncthreads) is ordered after all block data.
//  - consumers' data loads are relaxed agent atomics (sc-coherent, bypass
//    stale L2) issued only after the poll loop exits (control dep + asm barrier).
//  - poison 0xAAAAAAAA is negative -> `v >= epoch` keeps spinning.
__device__ __forceinline__ void gridBarrier(int* flags, int epoch, int bid, int tid) {
    drainVM();
    __syncthreads();
    if (tid == 0)
        __hip_atomic_store(flags + bid * 32, epoch, __ATOMIC_RELAXED,
                           __HIP_MEMORY_SCOPE_AGENT);
    if (tid < 64) {
        int spin = 0;
        for (;;) {
            bool ok = true;
            #pragma unroll
            for (int j = 0; j < 4; ++j) {
                int v = __hip_atomic_load(flags + (tid * 4 + j) * 32,
                                          __ATOMIC_RELAXED, __HIP_MEMORY_SCOPE_AGENT);
                ok &= (v >= epoch);
            }
            if (__all(ok)) break;
            if (++spin > (4 << 20)) break;   // fail loud, never hang
            __builtin_amdgcn_s_sleep(2);
        }
    }
    __syncthreads();
    asm volatile("" ::: "memory");
}

__global__ __launch_bounds__(NTHR, 2) void k_ode(
    const float* __restrict__ x,  const float* __restrict__ W1,
    const float* __restrict__ wt, const float* __restrict__ b1,
    const float* __restrict__ W2, const float* __restrict__ b2,
    float* __restrict__ out, float* __restrict__ yi_g,
    unsigned int* __restrict__ h_g, int* __restrict__ flags)
{
    __shared__ float ylds[D];   //  8 KB
    __shared__ float hlds[H];   // 32 KB

    const int tid = threadIdx.x, bid = blockIdx.x;
    const int wave = tid >> 6, lane = tid & 63;

    // ---- one-time: weights -> registers (fp16 pairs) ----
    // mv1: wave owns W1 rows r0..r0+3; lane owns float2-cols j*64+lane, j<16
    const int r0 = bid * 32 + wave * 4;
    __half2 w1f[4][16];
    #pragma unroll
    for (int r = 0; r < 4; ++r) {
        const float2* s = (const float2*)(W1 + (size_t)(r0 + r) * D);
        #pragma unroll
        for (int j = 0; j < 16; ++j) {
            float2 a = s[j * 64 + lane];              // coalesced 512B/wave
            w1f[r][j] = __floats2half2_rn(a.x, a.y);
        }
    }
    // mv2: wave owns W2 row row2; lane owns float2-cols j*64+lane, j<64
    const int row2 = bid * 8 + wave;
    __half2 w2f[64];
    {
        const float2* s = (const float2*)(W2 + (size_t)row2 * H);
        #pragma unroll
        for (int j = 0; j < 64; ++j) {
            float2 a = s[j * 64 + lane];
            w2f[j] = __floats2half2_rn(a.x, a.y);
        }
    }
    const float wt0 = wt[r0], wt1 = wt[r0+1], wt2 = wt[r0+2], wt3 = wt[r0+3];
    const float b10 = b1[r0], b11 = b1[r0+1], b12 = b1[r0+2], b13 = b1[r0+3];

    // tableau state for this wave's y-row, lane 0 only
    float yreg = x[row2];
    const float b2r = b2[row2];
    float k0 = 0, k1 = 0, k2 = 0, k3 = 0, k4 = 0;

    constexpr float dt = 1.0f / 64.0f;
    int ep = 1;

    #pragma unroll 1
    for (int step = 0; step < NSTEPS; ++step) {
        const float t = step * dt;
        #pragma unroll
        for (int st = 0; st < 6; ++st) {
            constexpr float Cc[6] = {0.f, 0.2f, 0.3f, 0.8f, 8.f/9.f, 1.f};
            const float s = 1.0f - (t + Cc[st] * dt);

            // ---- stage yi (2048 f32) -> LDS ----
            if (step == 0 && st == 0) {
                #pragma unroll
                for (int i = 0; i < 4; ++i)
                    ylds[tid + i * 512] = x[tid + i * 512];
            } else {
                #pragma unroll
                for (int i = 0; i < 4; ++i)
                    ylds[tid + i * 512] = __hip_atomic_load(
                        yi_g + tid + i * 512, __ATOMIC_RELAXED,
                        __HIP_MEMORY_SCOPE_AGENT);
            }
            __syncthreads();

            // ---- mv1: 4 W1 rows per wave ----
            float a0 = 0, a1 = 0, a2 = 0, a3 = 0;
            #pragma unroll
            for (int j = 0; j < 16; ++j) {
                float2 yv = ((const float2*)ylds)[j * 64 + lane];
                float2 f;
                f = __half22float2(w1f[0][j]); a0 = fmaf(f.x, yv.x, fmaf(f.y, yv.y, a0));
                f = __half22float2(w1f[1][j]); a1 = fmaf(f.x, yv.x, fmaf(f.y, yv.y, a1));
                f = __half22float2(w1f[2][j]); a2 = fmaf(f.x, yv.x, fmaf(f.y, yv.y, a2));
                f = __half22float2(w1f[3][j]); a3 = fmaf(f.x, yv.x, fmaf(f.y, yv.y, a3));
            }
            a0 = waveReduce64(a0); a1 = waveReduce64(a1);
            a2 = waveReduce64(a2); a3 = waveReduce64(a3);
            if (lane == 0) {
                float h0 = tanhf(fmaf(s, wt0, a0 + b10));
                float h1 = tanhf(fmaf(s, wt1, a1 + b11));
                float h2 = tanhf(fmaf(s, wt2, a2 + b12));
                float h3 = tanhf(fmaf(s, wt3, a3 + b13));
                __half2 lo = __floats2half2_rn(h0, h1);
                __half2 hi = __floats2half2_rn(h2, h3);
                unsigned long long pv =
                    ((unsigned long long)__builtin_bit_cast(unsigned int, hi) << 32) |
                    (unsigned long long)__builtin_bit_cast(unsigned int, lo);
                __hip_atomic_store((unsigned long long*)h_g + (bid * 8 + wave),
                                   pv, __ATOMIC_RELAXED, __HIP_MEMORY_SCOPE_AGENT);
            }
            gridBarrier(flags, ep++, bid, tid);

            // ---- stage h (8192 fp16 -> f32) -> LDS ----
            #pragma unroll
            for (int i = 0; i < 8; ++i) {
                unsigned int u = __hip_atomic_load(h_g + tid + i * 512,
                                   __ATOMIC_RELAXED, __HIP_MEMORY_SCOPE_AGENT);
                ((float2*)hlds)[tid + i * 512] =
                    __half22float2(__builtin_bit_cast(__half2, u));
            }
            __syncthreads();

            // ---- mv2: 1 W2 row per wave ----
            float acc = 0.f;
            #pragma unroll
            for (int j = 0; j < 64; ++j) {
                float2 hv = ((const float2*)hlds)[j * 64 + lane];
                float2 f = __half22float2(w2f[j]);
                acc = fmaf(f.x, hv.x, fmaf(f.y, hv.y, acc));
            }
            acc = waveReduce64(acc);

            // ---- tableau epilogue: lane 0 of the owning wave ----
            if (lane == 0) {
                const float k = -(acc + b2r);
                float yo = yreg;
                if (st == 0) { k0 = k;
                    yo = fmaf(dt * 0.2f, k0, yreg); }
                else if (st == 1) { k1 = k;
                    yo = yreg + dt * (3.f/40.f*k0 + 9.f/40.f*k1); }
                else if (st == 2) { k2 = k;
                    yo = yreg + dt * (44.f/45.f*k0 - 56.f/15.f*k1 + 32.f/9.f*k2); }
                else if (st == 3) { k3 = k;
                    yo = yreg + dt * (19372.f/6561.f*k0 - 25360.f/2187.f*k1
                                    + 64448.f/6561.f*k2 - 212.f/729.f*k3); }
                else if (st == 4) { k4 = k;
                    yo = yreg + dt * (9017.f/3168.f*k0 - 355.f/33.f*k1
                                    + 46732.f/5247.f*k2 + 49.f/176.f*k3
                                    - 5103.f/18656.f*k4); }
                else {
                    yreg = yreg + dt * (35.f/384.f*k0 + 500.f/1113.f*k2
                                      + 125.f/192.f*k3 - 2187.f/6784.f*k4
                                      + 11.f/84.f*k);
                    yo = yreg;
                    if (step == NSTEPS - 1) out[row2] = yreg;
                }
                __hip_atomic_store(yi_g + row2, yo, __ATOMIC_RELAXED,
                                   __HIP_MEMORY_SCOPE_AGENT);
            }
            if (!(step == NSTEPS - 1 && st == 5))   // last barrier elided
                gridBarrier(flags, ep++, bid, tid);
        }
    }
}

extern "C" void kernel_launch(void* const* d_in, const int* in_sizes, int n_in,
                              void* d_out, int out_size, void* d_ws, size_t ws_size,
                              hipStream_t stream) {
    const float* x  = (const float*)d_in[0];
    const float* W1 = (const float*)d_in[1];
    const float* wt = (const float*)d_in[2];
    const float* b1 = (const float*)d_in[3];
    const float* W2 = (const float*)d_in[4];
    const float* b2 = (const float*)d_in[5];
    float* out = (float*)d_out;

    float*        ws   = (float*)d_ws;
    float*        yi_g = ws;                          // [2048] f32
    unsigned int* h_g  = (unsigned int*)(ws + D);     // [4096] u32 (8192 fp16)
    int*          flags = (int*)((char*)(ws + D) + H * 2);  // 256 x 32 ints

    hipLaunchKernelGGL(k_ode, dim3(NBLK), dim3(NTHR), 0, stream,
                       x, W1, wt, b1, W2, b2, out, yi_g, h_g, flags);
}

// Round 8
// 3936.077 us; speedup vs baseline: 10.8361x; 2.4144x over previous
//
#include <hip/hip_runtime.h>
#include <hip/hip_fp16.h>

// Neural ODE (Dopri5, 64 steps), D=2048, H=8192.
// Round 8: persistent kernel, 256 blocks x 512 threads (1 block/CU).
// Round-7 counters showed the allocator clamps to the 128-VGPR granule and
// spills (VGPR_Count=128, 24.6us/stage serial scratch reloads). Fix: fit
// UNDER 128 VGPRs -- W1 slice in registers (64 half2/thread), W2 slice in
// LDS (128 KB fp16), h staged fp16 (16 KB), y f32 (8 KB) = 152 KB LDS.
// Fence-free grid barrier (relaxed agent atomics + vmcnt drain), proven
// correct in round 7 (absmax = fp16 signature 0.015625).

constexpr int D = 2048;
constexpr int H = 8192;
constexpr int NSTEPS = 64;
constexpr int NBLK = 256;
constexpr int NTHR = 512;

__device__ __forceinline__ float waveReduce64(float v) {
    #pragma unroll
    for (int off = 32; off; off >>= 1) v += __shfl_down(v, off, 64);
    return v;
}

__device__ __forceinline__ void drainVM() {
    asm volatile("s_waitcnt vmcnt(0)" ::: "memory");
}

// Flat grid barrier, relaxed agent atomics only (no cache-invalidating ops).
// Data stores are drained per-wave (vmcnt(0)) before __syncthreads, so the
// tid-0 flag store is ordered after all block data. Poison 0xAAAAAAAA is
// negative -> `v >= epoch` keeps spinning. Capped spin fails loud, not hung.
__device__ __forceinline__ void gridBarrier(int* flags, int epoch, int bid, int tid) {
    drainVM();
    __syncthreads();
    if (tid == 0)
        __hip_atomic_store(flags + bid * 32, epoch, __ATOMIC_RELAXED,
                           __HIP_MEMORY_SCOPE_AGENT);
    if (tid < 64) {
        int spin = 0;
        for (;;) {
            bool ok = true;
            #pragma unroll
            for (int j = 0; j < 4; ++j) {
                int v = __hip_atomic_load(flags + (tid * 4 + j) * 32,
                                          __ATOMIC_RELAXED, __HIP_MEMORY_SCOPE_AGENT);
                ok &= (v >= epoch);
            }
            if (__all(ok)) break;
            if (++spin > (1 << 20)) break;
            __builtin_amdgcn_s_sleep(1);
        }
    }
    __syncthreads();
    asm volatile("" ::: "memory");
}

__global__ __launch_bounds__(NTHR, 2) void k_ode(
    const float* __restrict__ x,  const float* __restrict__ W1,
    const float* __restrict__ wt, const float* __restrict__ b1,
    const float* __restrict__ W2, const float* __restrict__ b2,
    float* __restrict__ out, float* __restrict__ yi_g,
    unsigned int* __restrict__ h_g, int* __restrict__ flags)
{
    __shared__ __half2      w2lds[8][H / 2];  // 128 KB: block's 8 W2 rows, fp16
    __shared__ unsigned int hlds[H / 2];      //  16 KB: h as half2 pairs
    __shared__ float        ylds[D];          //   8 KB

    const int tid = threadIdx.x, bid = blockIdx.x;
    const int wave = tid >> 6, lane = tid & 63;

    // ---- one-time: W1 slice -> registers (64 half2/thread) ----
    // wave owns W1 rows r0..r0+3; lane owns element pairs (j*128+2*lane, +1)
    const int r0 = bid * 32 + wave * 4;
    __half2 w1f[4][16];
    #pragma unroll
    for (int r = 0; r < 4; ++r) {
        const float2* s = (const float2*)(W1 + (size_t)(r0 + r) * D);
        #pragma unroll
        for (int j = 0; j < 16; ++j) {
            float2 a = s[j * 64 + lane];              // coalesced 512B/wave
            w1f[r][j] = __floats2half2_rn(a.x, a.y);
        }
    }
    // ---- one-time: W2 slice -> LDS (each wave stages its own row) ----
    const int row2 = bid * 8 + wave;
    {
        const float2* s = (const float2*)(W2 + (size_t)row2 * H);
        #pragma unroll
        for (int j = 0; j < 64; ++j) {
            float2 a = s[j * 64 + lane];              // coalesced 512B/wave
            w2lds[wave][j * 64 + lane] = __floats2half2_rn(a.x, a.y);
        }
    }
    const float wt0 = wt[r0], wt1 = wt[r0+1], wt2 = wt[r0+2], wt3 = wt[r0+3];
    const float b10 = b1[r0], b11 = b1[r0+1], b12 = b1[r0+2], b13 = b1[r0+3];

    // tableau state for this wave's y-row (row2), lane 0 only
    float yreg = x[row2];
    const float b2r = b2[row2];
    float k0 = 0, k1 = 0, k2 = 0, k3 = 0, k4 = 0;

    constexpr float dt = 1.0f / 64.0f;
    int ep = 1;

    #pragma unroll 1
    for (int step = 0; step < NSTEPS; ++step) {
        const float t = step * dt;
        #pragma unroll
        for (int st = 0; st < 6; ++st) {
            constexpr float Cc[6] = {0.f, 0.2f, 0.3f, 0.8f, 8.f/9.f, 1.f};
            const float s = 1.0f - (t + Cc[st] * dt);

            // ---- stage yi (2048 f32) -> LDS ----
            if (step == 0 && st == 0) {
                #pragma unroll
                for (int i = 0; i < 4; ++i)
                    ylds[tid + i * 512] = x[tid + i * 512];
            } else {
                #pragma unroll
                for (int i = 0; i < 4; ++i)
                    ylds[tid + i * 512] = __hip_atomic_load(
                        yi_g + tid + i * 512, __ATOMIC_RELAXED,
                        __HIP_MEMORY_SCOPE_AGENT);
            }
            __syncthreads();

            // ---- mv1: 4 W1 rows per wave (weights in registers) ----
            float a0 = 0, a1 = 0, a2 = 0, a3 = 0;
            #pragma unroll
            for (int j = 0; j < 16; ++j) {
                float2 yv = ((const float2*)ylds)[j * 64 + lane];
                float2 f;
                f = __half22float2(w1f[0][j]); a0 = fmaf(f.x, yv.x, fmaf(f.y, yv.y, a0));
                f = __half22float2(w1f[1][j]); a1 = fmaf(f.x, yv.x, fmaf(f.y, yv.y, a1));
                f = __half22float2(w1f[2][j]); a2 = fmaf(f.x, yv.x, fmaf(f.y, yv.y, a2));
                f = __half22float2(w1f[3][j]); a3 = fmaf(f.x, yv.x, fmaf(f.y, yv.y, a3));
            }
            a0 = waveReduce64(a0); a1 = waveReduce64(a1);
            a2 = waveReduce64(a2); a3 = waveReduce64(a3);
            if (lane == 0) {
                float h0 = tanhf(fmaf(s, wt0, a0 + b10));
                float h1 = tanhf(fmaf(s, wt1, a1 + b11));
                float h2 = tanhf(fmaf(s, wt2, a2 + b12));
                float h3 = tanhf(fmaf(s, wt3, a3 + b13));
                __half2 lo = __floats2half2_rn(h0, h1);
                __half2 hi = __floats2half2_rn(h2, h3);
                unsigned long long pv =
                    ((unsigned long long)__builtin_bit_cast(unsigned int, hi) << 32) |
                    (unsigned long long)__builtin_bit_cast(unsigned int, lo);
                __hip_atomic_store((unsigned long long*)h_g + (bid * 8 + wave),
                                   pv, __ATOMIC_RELAXED, __HIP_MEMORY_SCOPE_AGENT);
            }
            gridBarrier(flags, ep++, bid, tid);

            // ---- stage h (4096 u32 = 8192 fp16) -> LDS, no conversion ----
            #pragma unroll
            for (int i = 0; i < 8; ++i)
                hlds[tid + i * 512] = __hip_atomic_load(h_g + tid + i * 512,
                                   __ATOMIC_RELAXED, __HIP_MEMORY_SCOPE_AGENT);
            __syncthreads();

            // ---- mv2: 1 W2 row per wave (weights in LDS, fp16) ----
            float acc = 0.f;
            #pragma unroll
            for (int j = 0; j < 64; ++j) {
                const int idx = j * 64 + lane;
                float2 wf = __half22float2(w2lds[wave][idx]);
                float2 hf = __half22float2(__builtin_bit_cast(__half2, hlds[idx]));
                acc = fmaf(wf.x, hf.x, fmaf(wf.y, hf.y, acc));
            }
            acc = waveReduce64(acc);

            // ---- tableau epilogue: lane 0 of the owning wave ----
            if (lane == 0) {
                const float k = -(acc + b2r);
                float yo = yreg;
                if (st == 0) { k0 = k;
                    yo = fmaf(dt * 0.2f, k0, yreg); }
                else if (st == 1) { k1 = k;
                    yo = yreg + dt * (3.f/40.f*k0 + 9.f/40.f*k1); }
                else if (st == 2) { k2 = k;
                    yo = yreg + dt * (44.f/45.f*k0 - 56.f/15.f*k1 + 32.f/9.f*k2); }
                else if (st == 3) { k3 = k;
                    yo = yreg + dt * (19372.f/6561.f*k0 - 25360.f/2187.f*k1
                                    + 64448.f/6561.f*k2 - 212.f/729.f*k3); }
                else if (st == 4) { k4 = k;
                    yo = yreg + dt * (9017.f/3168.f*k0 - 355.f/33.f*k1
                                    + 46732.f/5247.f*k2 + 49.f/176.f*k3
                                    - 5103.f/18656.f*k4); }
                else {
                    yreg = yreg + dt * (35.f/384.f*k0 + 500.f/1113.f*k2
                                      + 125.f/192.f*k3 - 2187.f/6784.f*k4
                                      + 11.f/84.f*k);
                    yo = yreg;
                    if (step == NSTEPS - 1) out[row2] = yreg;
                }
                __hip_atomic_store(yi_g + row2, yo, __ATOMIC_RELAXED,
                                   __HIP_MEMORY_SCOPE_AGENT);
            }
            if (!(step == NSTEPS - 1 && st == 5))   // last barrier elided
                gridBarrier(flags, ep++, bid, tid);
        }
    }
}

extern "C" void kernel_launch(void* const* d_in, const int* in_sizes, int n_in,
                              void* d_out, int out_size, void* d_ws, size_t ws_size,
                              hipStream_t stream) {
    const float* x  = (const float*)d_in[0];
    const float* W1 = (const float*)d_in[1];
    const float* wt = (const float*)d_in[2];
    const float* b1 = (const float*)d_in[3];
    const float* W2 = (const float*)d_in[4];
    const float* b2 = (const float*)d_in[5];
    float* out = (float*)d_out;

    float*        ws    = (float*)d_ws;
    float*        yi_g  = ws;                          // [2048] f32
    unsigned int* h_g   = (unsigned int*)(ws + D);     // [4096] u32 (8192 fp16)
    int*          flags = (int*)((char*)(ws + D) + H * 2);  // 256 x 32 ints

    hipLaunchKernelGGL(k_ode, dim3(NBLK), dim3(NTHR), 0, stream,
                       x, W1, wt, b1, W2, b2, out, yi_g, h_g, flags);
}